// Round 10
// baseline (253.863 us; speedup 1.0000x reference)
//
#include <hip/hip_runtime.h>

#define NN 30000
#define NE 120000
#define NG 256
#define FIN 16
#define HD 32
#define TOUT 10
#define EPSV 1e-5f
#define CAP 32        // bucket capacity per node (deg ~ Poisson(4); P(>=32) ~ 1e-16)
#define LGRID (NN / 16)   // 1875 fused-layer blocks

__device__ __forceinline__ void atomAddF(float* p, float v) {
    unsafeAtomicAdd(p, v);  // global_atomic_add_f32
}

// ===========================================================================
// Init: all DIRECT stores. cursor[d] = d*CAP; pooled = 0; done = 0; deg_g[g]
// via binary search on the sorted batch array.
// ===========================================================================
__global__ __launch_bounds__(256) void init_kernel(
    const int* __restrict__ batch,     // [NN] sorted
    int*   __restrict__ cursor,        // [NN]
    float* __restrict__ deg_g,         // [NG]
    float* __restrict__ pooled,        // [NG*HD]
    int*   __restrict__ done)          // [1]
{
    const int t = blockIdx.x * 256 + threadIdx.x;

    if (t < NN) cursor[t] = t * CAP;
    if (t < NG * HD) pooled[t] = 0.0f;
    if (t == 0) *done = 0;

    if (t < NG) {
        int lo = 0, hi = NN;
        while (lo < hi) { const int m = (lo + hi) >> 1;
                          if (batch[m] < t) lo = m + 1; else hi = m; }
        const int b0 = lo;
        lo = 0; hi = NN;
        while (lo < hi) { const int m = (lo + hi) >> 1;
                          if (batch[m] < t + 1) lo = m + 1; else hi = m; }
        deg_g[t] = (float)(lo - b0);
    }
}

// ---------------------------------------------------------------------------
// Scatter edges + edge attrs into per-node buckets (src_b / ea_b).
// ---------------------------------------------------------------------------
__global__ __launch_bounds__(256) void bucket_scatter(
    const int* __restrict__ eidx, const float* __restrict__ ea,
    int* __restrict__ cursor,
    int* __restrict__ src_b,      // [NN*CAP]
    float4* __restrict__ ea_b)    // [NN*CAP*2]
{
    const int e = blockIdx.x * 256 + threadIdx.x;
    if (e >= NE) return;
    const int d = eidx[NE + e];
    const int slot = atomicAdd(&cursor[d], 1);
    if (slot < d * CAP + CAP) {
        src_b[slot] = eidx[e];
        const float4* s4 = (const float4*)(ea + (size_t)e * 8);
        ea_b[2 * slot]     = s4[0];
        ea_b[2 * slot + 1] = s4[1];
    }
}

// ===========================================================================
// Fused layer (R9 structure) + FINAL: head folded in via last-block pattern.
//  - Address-first prefetch (R7) + full-wave 4-edge-ILP phase A (R3).
//  - Phase B: k split SPLIT ways per wave (4 for IN=32, 2 for IN=16);
//    ds_read_b128 carries SPLIT distinct addresses -> halves LDS instr count.
//  - FINAL: pooled atomics -> syncthreads (drains vmcnt) -> fence + done
//    atomic; last block runs the 256-graph MLP head inline (1 thread/graph,
//    volatile pooled reads).  Removes one dispatch + its gap.
// ===========================================================================
template<int IN, bool FINAL>
__global__ __launch_bounds__(256) void fused_layer(
    const float* __restrict__ hin,       // [NN, IN]
    const int*   __restrict__ src_b,     // [NN*CAP] bucketed src ids
    const float4* __restrict__ ea_b,     // [NN*CAP*2] bucketed edge attrs
    const int*   __restrict__ cursor,    // [NN] bucket end pointers
    const float* __restrict__ nn_w,      // [8*IN*32] flat k*32+o
    const float* __restrict__ nn_b,      // [IN*32]
    const float* __restrict__ root,      // [IN*32]
    const float* __restrict__ bias,      // [32]
    const int*   __restrict__ batch,
    const float* __restrict__ deg_g,     // [NG]
    const float* __restrict__ bn_g,
    const float* __restrict__ bn_b,
    const float* __restrict__ bn_m,
    const float* __restrict__ bn_v,
    float*       __restrict__ out,       // [NN,32] or pooled [NG,32]
    const float* __restrict__ mlp_w1,    // FINAL only
    const float* __restrict__ mlp_b1,
    const float* __restrict__ mlp_w2,
    const float* __restrict__ mlp_b2,
    float*       __restrict__ final_out, // [NG,TOUT]
    int*         __restrict__ done)      // [1]
{
    constexpr int K     = 10 * IN;
    constexpr int KQ    = K / 4;          // per-wave k slice
    constexpr int NQ    = 64 / IN;        // edge subgroups per node (4 or 2)
    constexpr int STEP  = 4 * NQ;         // edges per node per ILP round
    constexpr int SPLIT = (IN == 32) ? 4 : 2;   // k groups per wave
    constexpr int GRP   = 64 / SPLIT;     // lanes per group (16 or 32)
    constexpr int OPL   = 32 / GRP;       // outputs per lane (2 or 1)
    constexpr int CH    = KQ / SPLIT;     // k per group slice (=20 both)
    static_assert(CH % 4 == 0, "group k-slice must be float4-divisible");

    __shared__ __align__(16) float Tlds[16 * K];
    __shared__ float P[4 * 16 * 32];
    __shared__ int lastflag;

    const int tid = threadIdx.x;
    const int wv  = tid >> 6;
    const int l   = tid & 63;
    const int l5  = l & 31;
    const int pr  = l >> 5;
    const int b16 = blockIdx.x * 16;

    // ---- prefetch preamble: issue all far-memory touches for this thread's
    //      2 nodes (half-wave x j covers the wave's 4 nodes) ---------------
    int   p1c[2];
    float tea_pf[2], tx_pf[2], tx2_pf[2];
    #pragma unroll
    for (int j = 0; j < 2; ++j) {
        const int nloc = wv * 4 + j * 2 + pr;
        const int d    = b16 + nloc;
        const int p0   = d * CAP;
        int p1 = cursor[d];
        p1 = (p1 < p0 + CAP) ? p1 : (p0 + CAP);
        p1c[j] = p1;
        const int deg = p1 - p0;
        float tea = 0.0f, tx = 0.0f, tx2 = 0.0f;
        if (l5 < deg) {
            const int sl = p0 + l5;                       // coalesced
            const int sid = src_b[sl];                    // whole id list, 1 load
            tea = ((const float*)(ea_b + 2 * sl))[0];     // 64B line: A and B
            tx  = hin[(long)sid * IN];                    // x row, line 0
            if (IN == 32) tx2 = hin[(long)sid * IN + 16]; // x row, line 1
        }
        tea_pf[j] = tea; tx_pf[j] = tx; tx2_pf[j] = tx2;
    }

    // ---- W slice into registers (independent work under the prefetch) ----
    const int qg = l / GRP;               // k group 0..SPLIT-1
    const int om = l % GRP;               // output lane (o = om + p*GRP)
    const int kbase = wv * KQ + qg * CH;

    float Wreg[CH][OPL];
    #pragma unroll
    for (int kk = 0; kk < CH; ++kk) {
        const int k = kbase + kk;
        const float* src = (k < 8 * IN) ? (nn_w + k * 32)
                         : (k < 9 * IN) ? (nn_b + (k - 8 * IN) * 32)
                                        : (root + (k - 9 * IN) * 32);
        #pragma unroll
        for (int p = 0; p < OPL; ++p)
            Wreg[kk][p] = src[om + p * GRP];
    }

    // ---------------- phase A: full wave per node, 4-edge ILP batches ----
    {
        const int i = l & (IN - 1);
        const int q = l / IN;            // 0..NQ-1

        #pragma unroll
        for (int jj = 0; jj < 4; ++jj) {
            const int nloc = wv * 4 + jj;
            const int d    = b16 + nloc;
            const int p0   = d * CAP;
            // p1 lives in p1c[jj>>1] of the (jj&1) half-wave: broadcast it
            const int p1   = __shfl(p1c[jj >> 1], (jj & 1) << 5, 64);

            float t[9];
            #pragma unroll
            for (int f = 0; f < 9; ++f) t[f] = 0.0f;

            for (int base = p0 + q; base < p1; base += STEP) {
                float4 A[4], B[4];
                float  xv[4];
                // issue all loads for 4 independent edges first
                #pragma unroll
                for (int e = 0; e < 4; ++e) {
                    const int  pp = base + e * NQ;
                    const bool ok = pp < p1;
                    const int  pc = ok ? pp : p0;   // p0 valid: loop entered
                    A[e] = ea_b[2 * pc];
                    B[e] = ea_b[2 * pc + 1];
                    const int s = src_b[pc];
                    xv[e] = ok ? hin[(long)s * IN + i] : 0.0f;
                }
                #pragma unroll
                for (int e = 0; e < 4; ++e) {
                    t[0] = fmaf(A[e].x, xv[e], t[0]);
                    t[1] = fmaf(A[e].y, xv[e], t[1]);
                    t[2] = fmaf(A[e].z, xv[e], t[2]);
                    t[3] = fmaf(A[e].w, xv[e], t[3]);
                    t[4] = fmaf(B[e].x, xv[e], t[4]);
                    t[5] = fmaf(B[e].y, xv[e], t[5]);
                    t[6] = fmaf(B[e].z, xv[e], t[6]);
                    t[7] = fmaf(B[e].w, xv[e], t[7]);
                    t[8] += xv[e];
                }
            }

            // combine the NQ edge subgroups (same i, different q)
            if (IN == 16) {
                #pragma unroll
                for (int f = 0; f < 9; ++f) t[f] += __shfl_xor(t[f], 16, 64);
            }
            #pragma unroll
            for (int f = 0; f < 9; ++f) t[f] += __shfl_xor(t[f], 32, 64);

            if (l < IN) {
                float* tb = Tlds + nloc * K;
                #pragma unroll
                for (int f = 0; f < 9; ++f) tb[f * IN + i] = t[f];
                tb[9 * IN + i] = hin[(long)d * IN + i];   // own row (root)
            }
        }
    }
    // keep prefetch touches alive without earlier waits (rule #17)
    asm volatile("" :: "v"(tea_pf[0]), "v"(tea_pf[1]),
                       "v"(tx_pf[0]),  "v"(tx_pf[1]),
                       "v"(tx2_pf[0]), "v"(tx2_pf[1]));
    __syncthreads();

    // ---------------- phase B: SPLIT-way k groups, OPL outputs per lane ----
    #pragma unroll 2
    for (int n = 0; n < 16; ++n) {
        const float* tb = Tlds + n * K + kbase;
        float acc[OPL];
        #pragma unroll
        for (int p = 0; p < OPL; ++p) acc[p] = 0.0f;

        #pragma unroll
        for (int c = 0; c < CH / 4; ++c) {
            const float4 tv = *(const float4*)(tb + c * 4);
            #pragma unroll
            for (int p = 0; p < OPL; ++p) {
                acc[p] = fmaf(Wreg[4 * c + 0][p], tv.x, acc[p]);
                acc[p] = fmaf(Wreg[4 * c + 1][p], tv.y, acc[p]);
                acc[p] = fmaf(Wreg[4 * c + 2][p], tv.z, acc[p]);
                acc[p] = fmaf(Wreg[4 * c + 3][p], tv.w, acc[p]);
            }
        }
        // reduce across the SPLIT k-groups
        #pragma unroll
        for (int off = GRP; off < 64; off <<= 1) {
            #pragma unroll
            for (int p = 0; p < OPL; ++p)
                acc[p] += __shfl_xor(acc[p], off, 64);
        }
        if (l < GRP) {
            #pragma unroll
            for (int p = 0; p < OPL; ++p)
                P[(wv * 16 + n) * 32 + om + p * GRP] = acc[p];
        }
    }
    __syncthreads();

    // ---------------- reduce partials + epilogue ---------------------------
    #pragma unroll
    for (int r = 0; r < 2; ++r) {
        const int idx = r * 256 + tid;          // 512 (n,o) pairs
        const int n   = idx >> 5;
        const int oo  = idx & 31;
        float sum = bias[oo];
        #pragma unroll
        for (int ww = 0; ww < 4; ++ww)
            sum += P[(ww * 16 + n) * 32 + oo];
        const int d = b16 + n;
        const int g = batch[d];
        if (!FINAL) {
            float dg = deg_g[g];
            dg = dg > 0.0f ? dg : 1.0f;
            float v = sum * (1.0f / sqrtf(dg));
            const float s = bn_g[oo] / sqrtf(bn_v[oo] + EPSV);
            v = (v - bn_m[oo]) * s + bn_b[oo];
            out[(long)d * 32 + oo] = v > 0.0f ? v : 0.0f;
        } else {
            float v = sum;
            const int   g2 = __shfl(g, (tid & 63) ^ 32, 64);
            const float v2 = __shfl(v, (tid & 63) ^ 32, 64);
            bool do_store = true;
            if (g2 == g) {                  // merge adjacent-node pair
                if (tid & 32) do_store = false;
                else          v += v2;
            }
            if (do_store) atomAddF(&out[g * 32 + oo], v);
        }
    }

    // ---------------- FINAL: last block runs the MLP head ------------------
    if (FINAL) {
        __syncthreads();                       // drains this block's atomics
        if (tid == 0) {
            __threadfence();                   // device-scope visibility
            lastflag = (atomicAdd(done, 1) == LGRID - 1);
        }
        __syncthreads();
        if (lastflag) {
            const int g = tid;                 // 256 threads == NG graphs
            float cnt = deg_g[g];
            cnt = cnt > 1.0f ? cnt : 1.0f;

            volatile const float* pv = (volatile const float*)out;
            float p[HD];
            #pragma unroll
            for (int i = 0; i < HD; ++i) p[i] = pv[g * HD + i] / cnt;

            float hid[HD];
            #pragma unroll
            for (int j = 0; j < HD; ++j) {
                float a = mlp_b1[j];
                #pragma unroll
                for (int i = 0; i < HD; ++i)
                    a = fmaf(p[i], mlp_w1[i * HD + j], a);
                hid[j] = a > 0.0f ? a : 0.0f;
            }
            #pragma unroll
            for (int t2 = 0; t2 < TOUT; ++t2) {
                float a = mlp_b2[t2];
                #pragma unroll
                for (int j = 0; j < HD; ++j)
                    a = fmaf(hid[j], mlp_w2[j * TOUT + t2], a);
                final_out[g * TOUT + t2] = a;
            }
        }
    }
}

// ---------------------------------------------------------------------------
extern "C" void kernel_launch(void* const* d_in, const int* in_sizes, int n_in,
                              void* d_out, int out_size, void* d_ws, size_t ws_size,
                              hipStream_t stream)
{
    const float* x        = (const float*)d_in[0];
    const float* ea       = (const float*)d_in[1];
    const int*   eidx     = (const int*)  d_in[2];
    const int*   batch    = (const int*)  d_in[3];
    const float* c1_nn_w  = (const float*)d_in[4];
    const float* c1_nn_b  = (const float*)d_in[5];
    const float* c1_root  = (const float*)d_in[6];
    const float* c1_bias  = (const float*)d_in[7];
    const float* c2_nn_w  = (const float*)d_in[8];
    const float* c2_nn_b  = (const float*)d_in[9];
    const float* c2_root  = (const float*)d_in[10];
    const float* c2_bias  = (const float*)d_in[11];
    const float* c3_nn_w  = (const float*)d_in[12];
    const float* c3_nn_b  = (const float*)d_in[13];
    const float* c3_root  = (const float*)d_in[14];
    const float* c3_bias  = (const float*)d_in[15];
    const float* bn1_g    = (const float*)d_in[16];
    const float* bn1_b    = (const float*)d_in[17];
    const float* bn1_m    = (const float*)d_in[18];
    const float* bn1_v    = (const float*)d_in[19];
    const float* bn2_g    = (const float*)d_in[20];
    const float* bn2_b    = (const float*)d_in[21];
    const float* bn2_m    = (const float*)d_in[22];
    const float* bn2_v    = (const float*)d_in[23];
    const float* mlp_w1   = (const float*)d_in[24];
    const float* mlp_b1   = (const float*)d_in[25];
    const float* mlp_w2   = (const float*)d_in[26];
    const float* mlp_b2   = (const float*)d_in[27];
    float* out = (float*)d_out;

    // workspace layout (16B alignment preserved)
    float*  h1     = (float*)d_ws;                   // NN*32
    float*  h2     = h1 + NN * HD;                   // NN*32
    float4* ea_b   = (float4*)(h2 + NN * HD);        // NN*CAP*2 float4 (30.7MB)
    int*    src_b  = (int*)(ea_b + 2 * NN * CAP);    // NN*CAP
    int*    cursor = src_b + NN * CAP;               // NN
    float*  deg_g  = (float*)(cursor + NN);          // NG
    float*  pooled = deg_g + NG;                     // NG*32
    int*    done   = (int*)(pooled + NG * HD);       // 1 (+pad)

    const int egrid = (NE + 255) / 256;

    init_kernel<<<(NN + 255) / 256, 256, 0, stream>>>(batch, cursor, deg_g,
                                                      pooled, done);

    bucket_scatter<<<egrid, 256, 0, stream>>>(eidx, ea, cursor, src_b, ea_b);

    fused_layer<FIN, false><<<LGRID, 256, 0, stream>>>(
        x, src_b, ea_b, cursor, c1_nn_w, c1_nn_b, c1_root, c1_bias,
        batch, deg_g, bn1_g, bn1_b, bn1_m, bn1_v, h1,
        nullptr, nullptr, nullptr, nullptr, nullptr, nullptr);

    fused_layer<HD, false><<<LGRID, 256, 0, stream>>>(
        h1, src_b, ea_b, cursor, c2_nn_w, c2_nn_b, c2_root, c2_bias,
        batch, deg_g, bn2_g, bn2_b, bn2_m, bn2_v, h2,
        nullptr, nullptr, nullptr, nullptr, nullptr, nullptr);

    fused_layer<HD, true><<<LGRID, 256, 0, stream>>>(
        h2, src_b, ea_b, cursor, c3_nn_w, c3_nn_b, c3_root, c3_bias,
        batch, deg_g, nullptr, nullptr, nullptr, nullptr, pooled,
        mlp_w1, mlp_b1, mlp_w2, mlp_b2, out, done);
}

// Round 11
// 234.367 us; speedup vs baseline: 1.0832x; 1.0832x over previous
//
#include <hip/hip_runtime.h>

#define NN 30000
#define NE 120000
#define NG 256
#define FIN 16
#define HD 32
#define TOUT 10
#define EPSV 1e-5f
#define CAP 32        // bucket capacity per node (deg ~ Poisson(4); P(>=32) ~ 1e-16)

__device__ __forceinline__ void atomAddF(float* p, float v) {
    unsafeAtomicAdd(p, v);  // global_atomic_add_f32
}

// ===========================================================================
// Init: all DIRECT stores. cursor[d] = d*CAP; pooled = 0; deg_g[g] via binary
// search on the sorted batch array.
// ===========================================================================
__global__ __launch_bounds__(256) void init_kernel(
    const int* __restrict__ batch,     // [NN] sorted
    int*   __restrict__ cursor,        // [NN]
    float* __restrict__ deg_g,         // [NG]
    float* __restrict__ pooled)        // [NG*HD]
{
    const int t = blockIdx.x * 256 + threadIdx.x;

    if (t < NN) cursor[t] = t * CAP;
    if (t < NG * HD) pooled[t] = 0.0f;

    if (t < NG) {
        int lo = 0, hi = NN;
        while (lo < hi) { const int m = (lo + hi) >> 1;
                          if (batch[m] < t) lo = m + 1; else hi = m; }
        const int b0 = lo;
        lo = 0; hi = NN;
        while (lo < hi) { const int m = (lo + hi) >> 1;
                          if (batch[m] < t + 1) lo = m + 1; else hi = m; }
        deg_g[t] = (float)(lo - b0);
    }
}

// ---------------------------------------------------------------------------
// Scatter edges + edge attrs into per-node buckets (src_b / ea_b).
// ---------------------------------------------------------------------------
__global__ __launch_bounds__(256) void bucket_scatter(
    const int* __restrict__ eidx, const float* __restrict__ ea,
    int* __restrict__ cursor,
    int* __restrict__ src_b,      // [NN*CAP]
    float4* __restrict__ ea_b)    // [NN*CAP*2]
{
    const int e = blockIdx.x * 256 + threadIdx.x;
    if (e >= NE) return;
    const int d = eidx[NE + e];
    const int slot = atomicAdd(&cursor[d], 1);
    if (slot < d * CAP + CAP) {
        src_b[slot] = eidx[e];
        const float4* s4 = (const float4*)(ea + (size_t)e * 8);
        ea_b[2 * slot]     = s4[0];
        ea_b[2 * slot + 1] = s4[1];
    }
}

// ===========================================================================
// Fused layer (best-verified composition, R9):
//  - Address-first prefetch (R7, per-dispatch -10%).
//  - Phase A: full wave per node, 4-edge ILP batches (R3).
//  - Phase B: k split SPLIT ways per wave (4 for IN=32, 2 for IN=16);
//    the wave's ds_read_b128 carries SPLIT distinct addresses -> halves
//    phase-B LDS instruction count for IN=32.
//  LDS: IN=32: 20.5+8 = 28.7 KB; IN=16: 10.2+8 = 18.4 KB.
// ===========================================================================
template<int IN, bool FINAL>
__global__ __launch_bounds__(256) void fused_layer(
    const float* __restrict__ hin,       // [NN, IN]
    const int*   __restrict__ src_b,     // [NN*CAP] bucketed src ids
    const float4* __restrict__ ea_b,     // [NN*CAP*2] bucketed edge attrs
    const int*   __restrict__ cursor,    // [NN] bucket end pointers
    const float* __restrict__ nn_w,      // [8*IN*32] flat k*32+o
    const float* __restrict__ nn_b,      // [IN*32]
    const float* __restrict__ root,      // [IN*32]
    const float* __restrict__ bias,      // [32]
    const int*   __restrict__ batch,
    const float* __restrict__ deg_g,     // [NG]
    const float* __restrict__ bn_g,
    const float* __restrict__ bn_b,
    const float* __restrict__ bn_m,
    const float* __restrict__ bn_v,
    float*       __restrict__ out)       // [NN,32] or pooled [NG,32]
{
    constexpr int K     = 10 * IN;
    constexpr int KQ    = K / 4;          // per-wave k slice
    constexpr int NQ    = 64 / IN;        // edge subgroups per node (4 or 2)
    constexpr int STEP  = 4 * NQ;         // edges per node per ILP round
    constexpr int SPLIT = (IN == 32) ? 4 : 2;   // k groups per wave
    constexpr int GRP   = 64 / SPLIT;     // lanes per group (16 or 32)
    constexpr int OPL   = 32 / GRP;       // outputs per lane (2 or 1)
    constexpr int CH    = KQ / SPLIT;     // k per group slice (=20 both)
    static_assert(CH % 4 == 0, "group k-slice must be float4-divisible");

    __shared__ __align__(16) float Tlds[16 * K];
    __shared__ float P[4 * 16 * 32];

    const int tid = threadIdx.x;
    const int wv  = tid >> 6;
    const int l   = tid & 63;
    const int l5  = l & 31;
    const int pr  = l >> 5;
    const int b16 = blockIdx.x * 16;

    // ---- prefetch preamble: issue all far-memory touches for this thread's
    //      2 nodes (half-wave x j covers the wave's 4 nodes) ---------------
    int   p1c[2];
    float tea_pf[2], tx_pf[2], tx2_pf[2];
    #pragma unroll
    for (int j = 0; j < 2; ++j) {
        const int nloc = wv * 4 + j * 2 + pr;
        const int d    = b16 + nloc;
        const int p0   = d * CAP;
        int p1 = cursor[d];
        p1 = (p1 < p0 + CAP) ? p1 : (p0 + CAP);
        p1c[j] = p1;
        const int deg = p1 - p0;
        float tea = 0.0f, tx = 0.0f, tx2 = 0.0f;
        if (l5 < deg) {
            const int sl = p0 + l5;                       // coalesced
            const int sid = src_b[sl];                    // whole id list, 1 load
            tea = ((const float*)(ea_b + 2 * sl))[0];     // 64B line: A and B
            tx  = hin[(long)sid * IN];                    // x row, line 0
            if (IN == 32) tx2 = hin[(long)sid * IN + 16]; // x row, line 1
        }
        tea_pf[j] = tea; tx_pf[j] = tx; tx2_pf[j] = tx2;
    }

    // ---- W slice into registers (independent work under the prefetch) ----
    const int qg = l / GRP;               // k group 0..SPLIT-1
    const int om = l % GRP;               // output lane (o = om + p*GRP)
    const int kbase = wv * KQ + qg * CH;

    float Wreg[CH][OPL];
    #pragma unroll
    for (int kk = 0; kk < CH; ++kk) {
        const int k = kbase + kk;
        const float* src = (k < 8 * IN) ? (nn_w + k * 32)
                         : (k < 9 * IN) ? (nn_b + (k - 8 * IN) * 32)
                                        : (root + (k - 9 * IN) * 32);
        #pragma unroll
        for (int p = 0; p < OPL; ++p)
            Wreg[kk][p] = src[om + p * GRP];
    }

    // ---------------- phase A: full wave per node, 4-edge ILP batches ----
    {
        const int i = l & (IN - 1);
        const int q = l / IN;            // 0..NQ-1

        #pragma unroll
        for (int jj = 0; jj < 4; ++jj) {
            const int nloc = wv * 4 + jj;
            const int d    = b16 + nloc;
            const int p0   = d * CAP;
            // p1 lives in p1c[jj>>1] of the (jj&1) half-wave: broadcast it
            const int p1   = __shfl(p1c[jj >> 1], (jj & 1) << 5, 64);

            float t[9];
            #pragma unroll
            for (int f = 0; f < 9; ++f) t[f] = 0.0f;

            for (int base = p0 + q; base < p1; base += STEP) {
                float4 A[4], B[4];
                float  xv[4];
                // issue all loads for 4 independent edges first
                #pragma unroll
                for (int e = 0; e < 4; ++e) {
                    const int  pp = base + e * NQ;
                    const bool ok = pp < p1;
                    const int  pc = ok ? pp : p0;   // p0 valid: loop entered
                    A[e] = ea_b[2 * pc];
                    B[e] = ea_b[2 * pc + 1];
                    const int s = src_b[pc];
                    xv[e] = ok ? hin[(long)s * IN + i] : 0.0f;
                }
                #pragma unroll
                for (int e = 0; e < 4; ++e) {
                    t[0] = fmaf(A[e].x, xv[e], t[0]);
                    t[1] = fmaf(A[e].y, xv[e], t[1]);
                    t[2] = fmaf(A[e].z, xv[e], t[2]);
                    t[3] = fmaf(A[e].w, xv[e], t[3]);
                    t[4] = fmaf(B[e].x, xv[e], t[4]);
                    t[5] = fmaf(B[e].y, xv[e], t[5]);
                    t[6] = fmaf(B[e].z, xv[e], t[6]);
                    t[7] = fmaf(B[e].w, xv[e], t[7]);
                    t[8] += xv[e];
                }
            }

            // combine the NQ edge subgroups (same i, different q)
            if (IN == 16) {
                #pragma unroll
                for (int f = 0; f < 9; ++f) t[f] += __shfl_xor(t[f], 16, 64);
            }
            #pragma unroll
            for (int f = 0; f < 9; ++f) t[f] += __shfl_xor(t[f], 32, 64);

            if (l < IN) {
                float* tb = Tlds + nloc * K;
                #pragma unroll
                for (int f = 0; f < 9; ++f) tb[f * IN + i] = t[f];
                tb[9 * IN + i] = hin[(long)d * IN + i];   // own row (root)
            }
        }
    }
    // keep prefetch touches alive without earlier waits (rule #17)
    asm volatile("" :: "v"(tea_pf[0]), "v"(tea_pf[1]),
                       "v"(tx_pf[0]),  "v"(tx_pf[1]),
                       "v"(tx2_pf[0]), "v"(tx2_pf[1]));
    __syncthreads();

    // ---------------- phase B: SPLIT-way k groups, OPL outputs per lane ----
    #pragma unroll 2
    for (int n = 0; n < 16; ++n) {
        const float* tb = Tlds + n * K + kbase;
        float acc[OPL];
        #pragma unroll
        for (int p = 0; p < OPL; ++p) acc[p] = 0.0f;

        #pragma unroll
        for (int c = 0; c < CH / 4; ++c) {
            const float4 tv = *(const float4*)(tb + c * 4);
            #pragma unroll
            for (int p = 0; p < OPL; ++p) {
                acc[p] = fmaf(Wreg[4 * c + 0][p], tv.x, acc[p]);
                acc[p] = fmaf(Wreg[4 * c + 1][p], tv.y, acc[p]);
                acc[p] = fmaf(Wreg[4 * c + 2][p], tv.z, acc[p]);
                acc[p] = fmaf(Wreg[4 * c + 3][p], tv.w, acc[p]);
            }
        }
        // reduce across the SPLIT k-groups
        #pragma unroll
        for (int off = GRP; off < 64; off <<= 1) {
            #pragma unroll
            for (int p = 0; p < OPL; ++p)
                acc[p] += __shfl_xor(acc[p], off, 64);
        }
        if (l < GRP) {
            #pragma unroll
            for (int p = 0; p < OPL; ++p)
                P[(wv * 16 + n) * 32 + om + p * GRP] = acc[p];
        }
    }
    __syncthreads();

    // ---------------- reduce partials + epilogue ---------------------------
    #pragma unroll
    for (int r = 0; r < 2; ++r) {
        const int idx = r * 256 + tid;          // 512 (n,o) pairs
        const int n   = idx >> 5;
        const int oo  = idx & 31;
        float sum = bias[oo];
        #pragma unroll
        for (int ww = 0; ww < 4; ++ww)
            sum += P[(ww * 16 + n) * 32 + oo];
        const int d = b16 + n;
        const int g = batch[d];
        if (!FINAL) {
            float dg = deg_g[g];
            dg = dg > 0.0f ? dg : 1.0f;
            float v = sum * (1.0f / sqrtf(dg));
            const float s = bn_g[oo] / sqrtf(bn_v[oo] + EPSV);
            v = (v - bn_m[oo]) * s + bn_b[oo];
            out[(long)d * 32 + oo] = v > 0.0f ? v : 0.0f;
        } else {
            float v = sum;
            const int   g2 = __shfl(g, (tid & 63) ^ 32, 64);
            const float v2 = __shfl(v, (tid & 63) ^ 32, 64);
            bool do_store = true;
            if (g2 == g) {                  // merge adjacent-node pair
                if (tid & 32) do_store = false;
                else          v += v2;
            }
            if (do_store) atomAddF(&out[g * 32 + oo], v);
        }
    }
}

// ---------------------------------------------------------------------------
// Head: pooled/cnt -> relu(@w1+b1) @ w2 + b2. One thread per graph.
// ---------------------------------------------------------------------------
__global__ __launch_bounds__(64) void head_kernel(
    const float* __restrict__ pooled,
    const float* __restrict__ deg,
    const float* __restrict__ w1,
    const float* __restrict__ b1,
    const float* __restrict__ w2,
    const float* __restrict__ b2,
    float*       __restrict__ out)
{
    const int g = blockIdx.x * 64 + threadIdx.x;
    if (g >= NG) return;
    float cnt = deg[g];
    cnt = cnt > 1.0f ? cnt : 1.0f;

    float p[HD];
    #pragma unroll
    for (int i = 0; i < HD; ++i) p[i] = pooled[g * HD + i] / cnt;

    float hid[HD];
    #pragma unroll
    for (int j = 0; j < HD; ++j) {
        float a = b1[j];
        #pragma unroll
        for (int i = 0; i < HD; ++i)
            a = fmaf(p[i], w1[i * HD + j], a);
        hid[j] = a > 0.0f ? a : 0.0f;
    }
    #pragma unroll
    for (int t = 0; t < TOUT; ++t) {
        float a = b2[t];
        #pragma unroll
        for (int j = 0; j < HD; ++j)
            a = fmaf(hid[j], w2[j * TOUT + t], a);
        out[g * TOUT + t] = a;
    }
}

// ---------------------------------------------------------------------------
extern "C" void kernel_launch(void* const* d_in, const int* in_sizes, int n_in,
                              void* d_out, int out_size, void* d_ws, size_t ws_size,
                              hipStream_t stream)
{
    const float* x        = (const float*)d_in[0];
    const float* ea       = (const float*)d_in[1];
    const int*   eidx     = (const int*)  d_in[2];
    const int*   batch    = (const int*)  d_in[3];
    const float* c1_nn_w  = (const float*)d_in[4];
    const float* c1_nn_b  = (const float*)d_in[5];
    const float* c1_root  = (const float*)d_in[6];
    const float* c1_bias  = (const float*)d_in[7];
    const float* c2_nn_w  = (const float*)d_in[8];
    const float* c2_nn_b  = (const float*)d_in[9];
    const float* c2_root  = (const float*)d_in[10];
    const float* c2_bias  = (const float*)d_in[11];
    const float* c3_nn_w  = (const float*)d_in[12];
    const float* c3_nn_b  = (const float*)d_in[13];
    const float* c3_root  = (const float*)d_in[14];
    const float* c3_bias  = (const float*)d_in[15];
    const float* bn1_g    = (const float*)d_in[16];
    const float* bn1_b    = (const float*)d_in[17];
    const float* bn1_m    = (const float*)d_in[18];
    const float* bn1_v    = (const float*)d_in[19];
    const float* bn2_g    = (const float*)d_in[20];
    const float* bn2_b    = (const float*)d_in[21];
    const float* bn2_m    = (const float*)d_in[22];
    const float* bn2_v    = (const float*)d_in[23];
    const float* mlp_w1   = (const float*)d_in[24];
    const float* mlp_b1   = (const float*)d_in[25];
    const float* mlp_w2   = (const float*)d_in[26];
    const float* mlp_b2   = (const float*)d_in[27];
    float* out = (float*)d_out;

    // workspace layout (16B alignment preserved)
    float*  h1     = (float*)d_ws;                   // NN*32
    float*  h2     = h1 + NN * HD;                   // NN*32
    float4* ea_b   = (float4*)(h2 + NN * HD);        // NN*CAP*2 float4 (30.7MB)
    int*    src_b  = (int*)(ea_b + 2 * NN * CAP);    // NN*CAP
    int*    cursor = src_b + NN * CAP;               // NN
    float*  deg_g  = (float*)(cursor + NN);          // NG
    float*  pooled = deg_g + NG;                     // NG*32

    const int egrid = (NE + 255) / 256;

    init_kernel<<<(NN + 255) / 256, 256, 0, stream>>>(batch, cursor, deg_g, pooled);

    bucket_scatter<<<egrid, 256, 0, stream>>>(eidx, ea, cursor, src_b, ea_b);

    const int lgrid = NN / 16;  // 1875 blocks, 16 nodes each

    fused_layer<FIN, false><<<lgrid, 256, 0, stream>>>(
        x, src_b, ea_b, cursor, c1_nn_w, c1_nn_b, c1_root, c1_bias,
        batch, deg_g, bn1_g, bn1_b, bn1_m, bn1_v, h1);

    fused_layer<HD, false><<<lgrid, 256, 0, stream>>>(
        h1, src_b, ea_b, cursor, c2_nn_w, c2_nn_b, c2_root, c2_bias,
        batch, deg_g, bn2_g, bn2_b, bn2_m, bn2_v, h2);

    fused_layer<HD, true><<<lgrid, 256, 0, stream>>>(
        h2, src_b, ea_b, cursor, c3_nn_w, c3_nn_b, c3_root, c3_bias,
        batch, deg_g, nullptr, nullptr, nullptr, nullptr, pooled);

    head_kernel<<<(NG + 63) / 64, 64, 0, stream>>>(pooled, deg_g, mlp_w1, mlp_b1,
                                                   mlp_w2, mlp_b2, out);
}